// Round 1
// baseline (32.400 us; speedup 1.0000x reference)
//
#include <hip/hip_runtime.h>

// YOLOv3 dense decode, 3 scales. Inputs (f32):
//  d_in[0] output_13 [32,255,13,13], d_in[1] output_26 [32,255,26,26],
//  d_in[2] output_52 [32,255,52,52], d_in[3..5] anchors [3,2] each,
//  d_in[6] thresh scalar.
// Output (f32 flat): boxes [340704,6] then valid [340704] (0.0/1.0).

constexpr int BATCH = 32;
constexpr int NCLS  = 80;
constexpr int HW13  = 13 * 13;   // 169
constexpr int HW26  = 26 * 26;   // 676
constexpr int HW52  = 52 * 52;   // 2704
constexpr int N13   = BATCH * 3 * HW13;   // 16224
constexpr int N26   = BATCH * 3 * HW26;   // 64896
constexpr int N52   = BATCH * 3 * HW52;   // 259584
constexpr int NTOT  = N13 + N26 + N52;    // 340704

template <int HW, int W>
__device__ __forceinline__ void decode_one(
    const float* __restrict__ in, const float* __restrict__ anc,
    float t, int li, int rowofs, float th,
    float* __restrict__ boxes, float* __restrict__ valid)
{
    // hw fastest so consecutive lanes read consecutive addresses (coalesced)
    const int hw   = li % HW;
    const int rest = li / HW;
    const int a    = rest % 3;
    const int b    = rest / 3;
    const int x    = hw % W;
    const int y    = hw / W;

    const float* p = in + (size_t)(b * 255 + a * 85) * HW + hw;

    const float t0 = p[0];
    const float t1 = p[(size_t)1 * HW];
    const float t2 = p[(size_t)2 * HW];
    const float t3 = p[(size_t)3 * HW];
    const float t4 = p[(size_t)4 * HW];

    // argmax over classes, first-max semantics (strict >)
    float best = p[(size_t)5 * HW];
    int cls = 0;
    for (int k = 1; k < NCLS; ++k) {
        const float v = p[(size_t)(5 + k) * HW];
        if (v > best) { best = v; cls = k; }
    }

    const float conf = 1.0f / (1.0f + expf(-t0));
    const float cx   = ((float)x + 1.0f / (1.0f + expf(-t1))) * t;
    const float cy   = ((float)y + 1.0f / (1.0f + expf(-t2))) * t;
    const float w    = anc[a * 2 + 0] * expf(t3);
    const float h    = anc[a * 2 + 1] * expf(t4);
    const float x1   = cx - w * 0.5f;
    const float y1   = cy - h * 0.5f;
    const float x2   = x1 + w;
    const float y2   = y1 + h;

    // reference row order within a scale: (b, y, x, a) with a fastest
    const int row = rowofs + (b * HW + hw) * 3 + a;
    float* o = boxes + (size_t)row * 6;
    o[0] = conf; o[1] = x1; o[2] = y1; o[3] = x2; o[4] = y2; o[5] = (float)cls;
    valid[row] = conf > th ? 1.0f : 0.0f;
}

__global__ __launch_bounds__(256) void yolo_decode_kernel(
    const float* __restrict__ in13, const float* __restrict__ in26,
    const float* __restrict__ in52,
    const float* __restrict__ a13, const float* __restrict__ a26,
    const float* __restrict__ a52,
    const float* __restrict__ pth, float* __restrict__ out)
{
    const int i = blockIdx.x * blockDim.x + threadIdx.x;
    if (i >= NTOT) return;
    const float th = *pth;
    float* boxes = out;
    float* valid = out + (size_t)NTOT * 6;

    if (i < N13) {
        decode_one<HW13, 13>(in13, a13, 32.0f, i, 0, th, boxes, valid);
    } else if (i < N13 + N26) {
        decode_one<HW26, 26>(in26, a26, 16.0f, i - N13, N13, th, boxes, valid);
    } else {
        decode_one<HW52, 52>(in52, a52, 8.0f, i - (N13 + N26), N13 + N26, th, boxes, valid);
    }
}

extern "C" void kernel_launch(void* const* d_in, const int* in_sizes, int n_in,
                              void* d_out, int out_size, void* d_ws, size_t ws_size,
                              hipStream_t stream) {
    const float* in13 = (const float*)d_in[0];
    const float* in26 = (const float*)d_in[1];
    const float* in52 = (const float*)d_in[2];
    const float* a13  = (const float*)d_in[3];
    const float* a26  = (const float*)d_in[4];
    const float* a52  = (const float*)d_in[5];
    const float* pth  = (const float*)d_in[6];
    float* out = (float*)d_out;

    const int block = 256;
    const int grid  = (NTOT + block - 1) / block;
    yolo_decode_kernel<<<grid, block, 0, stream>>>(in13, in26, in52,
                                                   a13, a26, a52, pth, out);
}

// Round 2
// 28.892 us; speedup vs baseline: 1.1214x; 1.1214x over previous
//
#include <hip/hip_runtime.h>

// YOLOv3 dense decode, 3 scales. Inputs (f32):
//  d_in[0] output_13 [32,255,13,13], d_in[1] output_26 [32,255,26,26],
//  d_in[2] output_52 [32,255,52,52], d_in[3..5] anchors [3,2] each,
//  d_in[6] thresh scalar.
// Output (f32 flat): boxes [340704,6] then valid [340704] (0.0/1.0).
//
// Structure: blockDim=192 (3 waves). Wave w = anchor a (wave-uniform), 64
// lanes = 64 consecutive hw chunks. Reads: float4 per lane (scales 26/52),
// fully coalesced 1KB/wave/instr. Writes: one block fills one contiguous
// output region (all 3 anchors of the same hw range) -> no partial-line RMW.

constexpr int NCLS  = 80;
constexpr int BATCH = 32;
constexpr int HW13  = 169;
constexpr int HW26  = 676;
constexpr int HW52  = 2704;
constexpr int N13   = BATCH * 3 * HW13;   // 16224
constexpr int N26   = BATCH * 3 * HW26;   // 64896
constexpr int N52   = BATCH * 3 * HW52;   // 259584
constexpr int NTOT  = N13 + N26 + N52;    // 340704
constexpr int R13   = 0;
constexpr int R26   = N13;
constexpr int R52   = N13 + N26;

constexpr int OUT13 = (HW13 + 63) / 64;        // 3  (scalar path, per-hw)
constexpr int OUT26 = (HW26 / 4 + 63) / 64;    // 3  (float4 path, per 4-hw chunk)
constexpr int OUT52 = (HW52 / 4 + 63) / 64;    // 11
constexpr int B13   = BATCH * OUT13;           // 96
constexpr int B26   = BATCH * OUT26;           // 96
constexpr int B52   = BATCH * OUT52;           // 352
constexpr int NBLK  = B13 + B26 + B52;         // 544

__device__ __forceinline__ float sigm(float x) { return 1.0f / (1.0f + expf(-x)); }

// ---------- scalar path (scale 13: HW odd, float4 misaligned) ----------
template <int HW, int W>
__device__ __forceinline__ void decode_scalar(
    const float* __restrict__ in, const float* __restrict__ anc,
    float t, int b, int a, int hw, int rowofs, float th,
    float* __restrict__ boxes, float* __restrict__ valid)
{
    const int x = hw % W;
    const int y = hw / W;
    const float* p = in + (size_t)(b * 255 + a * 85) * HW + hw;

    const float t0 = p[0];
    const float t1 = p[(size_t)1 * HW];
    const float t2 = p[(size_t)2 * HW];
    const float t3 = p[(size_t)3 * HW];
    const float t4 = p[(size_t)4 * HW];

    float best = p[(size_t)5 * HW];
    int cls = 0;
#pragma unroll
    for (int k = 1; k < NCLS; ++k) {
        const float v = p[(size_t)(5 + k) * HW];
        cls  = v > best ? k : cls;
        best = fmaxf(v, best);
    }

    const float aw = anc[a * 2 + 0], ah = anc[a * 2 + 1];
    const float conf = sigm(t0);
    const float cx   = ((float)x + sigm(t1)) * t;
    const float cy   = ((float)y + sigm(t2)) * t;
    const float w    = aw * expf(t3);
    const float h    = ah * expf(t4);
    const float x1   = cx - w * 0.5f;
    const float y1   = cy - h * 0.5f;

    const int row = rowofs + (b * HW + hw) * 3 + a;
    float* o = boxes + (size_t)row * 6;
    o[0] = conf; o[1] = x1; o[2] = y1; o[3] = x1 + w; o[4] = y1 + h; o[5] = (float)cls;
    valid[row] = conf > th ? 1.0f : 0.0f;
}

// ---------- float4 path (scales 26/52: HW % 4 == 0, rows 16B-aligned) ----------
template <int HW, int W>
__device__ __forceinline__ void decode_vec4(
    const float* __restrict__ in, const float* __restrict__ anc,
    float t, int b, int a, int c, int rowofs, float th,
    float* __restrict__ boxes, float* __restrict__ valid)
{
    constexpr int HWc = HW / 4;
    const float4* __restrict__ p =
        reinterpret_cast<const float4*>(in + (size_t)(b * 255 + a * 85) * HW) + c;

    const float4 t0 = p[0];
    const float4 t1 = p[(size_t)1 * HWc];
    const float4 t2 = p[(size_t)2 * HWc];
    const float4 t3 = p[(size_t)3 * HWc];
    const float4 t4 = p[(size_t)4 * HWc];

    float4 bv = p[(size_t)5 * HWc];
    float b0 = bv.x, b1 = bv.y, b2 = bv.z, b3 = bv.w;
    int c0 = 0, c1 = 0, c2 = 0, c3 = 0;
#pragma unroll
    for (int k = 1; k < NCLS; ++k) {
        const float4 v = p[(size_t)(5 + k) * HWc];
        c0 = v.x > b0 ? k : c0;  b0 = fmaxf(v.x, b0);
        c1 = v.y > b1 ? k : c1;  b1 = fmaxf(v.y, b1);
        c2 = v.z > b2 ? k : c2;  b2 = fmaxf(v.z, b2);
        c3 = v.w > b3 ? k : c3;  b3 = fmaxf(v.w, b3);
    }

    const float aw = anc[a * 2 + 0], ah = anc[a * 2 + 1];

#define EMIT(j, s0, s1, s2, s3, s4, cc)                                   \
    {                                                                     \
        const int hw = 4 * c + (j);                                       \
        const int x = hw % W;                                             \
        const int y = hw / W;                                             \
        const float conf = sigm(s0);                                      \
        const float cx = ((float)x + sigm(s1)) * t;                       \
        const float cy = ((float)y + sigm(s2)) * t;                       \
        const float w_ = aw * expf(s3);                                   \
        const float h_ = ah * expf(s4);                                   \
        const float x1 = cx - w_ * 0.5f;                                  \
        const float y1 = cy - h_ * 0.5f;                                  \
        const int row = rowofs + (b * HW + hw) * 3 + a;                   \
        float* o = boxes + (size_t)row * 6;                               \
        o[0] = conf; o[1] = x1; o[2] = y1;                                \
        o[3] = x1 + w_; o[4] = y1 + h_; o[5] = (float)(cc);               \
        valid[row] = conf > th ? 1.0f : 0.0f;                             \
    }

    EMIT(0, t0.x, t1.x, t2.x, t3.x, t4.x, c0);
    EMIT(1, t0.y, t1.y, t2.y, t3.y, t4.y, c1);
    EMIT(2, t0.z, t1.z, t2.z, t3.z, t4.z, c2);
    EMIT(3, t0.w, t1.w, t2.w, t3.w, t4.w, c3);
#undef EMIT
}

__global__ __launch_bounds__(192) void yolo_decode_kernel(
    const float* __restrict__ in13, const float* __restrict__ in26,
    const float* __restrict__ in52,
    const float* __restrict__ a13, const float* __restrict__ a26,
    const float* __restrict__ a52,
    const float* __restrict__ pth, float* __restrict__ out)
{
    const int a    = threadIdx.x >> 6;   // wave index = anchor (wave-uniform)
    const int lane = threadIdx.x & 63;
    const float th = *pth;
    float* boxes = out;
    float* valid = out + (size_t)NTOT * 6;

    int blk = blockIdx.x;
    if (blk < B13) {
        const int b  = blk / OUT13;
        const int co = blk % OUT13;
        const int hw = co * 64 + lane;
        if (hw >= HW13) return;
        decode_scalar<HW13, 13>(in13, a13, 32.0f, b, a, hw, R13, th, boxes, valid);
    } else if (blk < B13 + B26) {
        blk -= B13;
        const int b  = blk / OUT26;
        const int co = blk % OUT26;
        const int c  = co * 64 + lane;
        if (c >= HW26 / 4) return;
        decode_vec4<HW26, 26>(in26, a26, 16.0f, b, a, c, R26, th, boxes, valid);
    } else {
        blk -= (B13 + B26);
        const int b  = blk / OUT52;
        const int co = blk % OUT52;
        const int c  = co * 64 + lane;
        if (c >= HW52 / 4) return;
        decode_vec4<HW52, 52>(in52, a52, 8.0f, b, a, c, R52, th, boxes, valid);
    }
}

extern "C" void kernel_launch(void* const* d_in, const int* in_sizes, int n_in,
                              void* d_out, int out_size, void* d_ws, size_t ws_size,
                              hipStream_t stream) {
    const float* in13 = (const float*)d_in[0];
    const float* in26 = (const float*)d_in[1];
    const float* in52 = (const float*)d_in[2];
    const float* a13  = (const float*)d_in[3];
    const float* a26  = (const float*)d_in[4];
    const float* a52  = (const float*)d_in[5];
    const float* pth  = (const float*)d_in[6];
    float* out = (float*)d_out;

    yolo_decode_kernel<<<NBLK, 192, 0, stream>>>(in13, in26, in52,
                                                 a13, a26, a52, pth, out);
}